// Round 13
// baseline (83.748 us; speedup 1.0000x reference)
//
#include <hip/hip_runtime.h>

#define DM 1024
#define NHEADS 16
#define NKVH 4
#define HDIM 64
#define NB 2
#define SEQ 2048
#define MTOK (NB*SEQ)

typedef __attribute__((ext_vector_type(4))) float f32x4;
typedef __attribute__((ext_vector_type(8))) short short8;
typedef unsigned short u16;
typedef unsigned int u32;

__device__ __forceinline__ u16 f2b(float f) {
  u32 i; __builtin_memcpy(&i, &f, 4);
  u32 r = i + 0x7fffu + ((i >> 16) & 1u);
  return (u16)(r >> 16);
}
__device__ __forceinline__ u32 cvtpk(float a, float b) {  // low16=bf16(a), high16=bf16(b)
  u32 r; asm("v_cvt_pk_bf16_f32 %0, %1, %2" : "=v"(r) : "v"(a), "v"(b)); return r;
}
__device__ __forceinline__ float fexp2(float x) {  // raw v_exp_f32 (softmax-safe)
  float r; asm("v_exp_f32 %0, %1" : "=v"(r) : "v"(x)); return r;
}
__device__ __forceinline__ void gload16(const void* g, void* l) {
  __builtin_amdgcn_global_load_lds((const __attribute__((address_space(1))) u32*)g,
                                   (__attribute__((address_space(3))) u32*)l, 16, 0, 0);
}

// ---------------- fused fp32 -> bf16 convert (all 7 tensors, one launch) ----------------
__device__ __forceinline__ void cvt8(const float* __restrict__ src, u16* __restrict__ dst, int i) {
  float4 a = *(const float4*)(src + i);
  float4 b = *(const float4*)(src + i + 4);
  uint4 pk;
  pk.x = cvtpk(a.x, a.y);
  pk.y = cvtpk(a.z, a.w);
  pk.z = cvtpk(b.x, b.y);
  pk.w = cvtpk(b.z, b.w);
  *(uint4*)(dst + i) = pk;
}

__global__ __launch_bounds__(256) void cvt_all(const float* __restrict__ q, const float* __restrict__ k,
                                               const float* __restrict__ v, const float* __restrict__ wq,
                                               const float* __restrict__ wk, const float* __restrict__ wv,
                                               const float* __restrict__ wo, u16* oq, u16* ok, u16* ov,
                                               u16* owq, u16* owk, u16* owv, u16* owo) {
  const int ACT = (MTOK * DM) / 2048;  // 2048 blocks per activation tensor
  const int BIG = (DM * DM) / 2048;    // 512
  const int SML = (256 * DM) / 2048;   // 128
  int bid = blockIdx.x;
  const float* s; u16* d;
  if (bid < ACT) { s = q; d = oq; }
  else if (bid < 2 * ACT) { s = k; d = ok; bid -= ACT; }
  else if (bid < 3 * ACT) { s = v; d = ov; bid -= 2 * ACT; }
  else {
    bid -= 3 * ACT;
    if (bid < BIG) { s = wq; d = owq; }
    else if (bid < 2 * BIG) { s = wo; d = owo; bid -= BIG; }
    else if (bid < 2 * BIG + SML) { s = wk; d = owk; bid -= 2 * BIG; }
    else { s = wv; d = owv; bid -= 2 * BIG + SML; }
  }
  cvt8(s, d, (bid * 256 + threadIdx.x) * 8);
}

// ---- m97-style bf16 tile staging: NR rows x 64 cols, source-swizzled (T21) ----
template<int NR>
__device__ __forceinline__ void stage_tile(const u16* __restrict__ src, int k0, u16* lds,
                                           int w, int lane) {
#pragma unroll
  for (int i = 0; i < NR / 32; i++) {
    const int base = (i * 4 + w) * 1024;          // byte offset (wave-uniform)
    const int row = (base >> 7) + (lane >> 3);    // 128B per row
    const int g = lane & 7;
    gload16(src + (size_t)row * DM + k0 + ((g ^ (row & 7)) << 3), (char*)lds + base);
  }
}
__device__ __forceinline__ short8 lds_frag(const u16* L, int row, int gr) {
  return *(const short8*)(L + row * 64 + ((gr ^ (row & 7)) << 3));
}

// ---------------- fused QKV projection GEMM (bf16) + RoPE + V-transpose ----------------
__global__ __launch_bounds__(256, 3) void gemm_qkv(const u16* __restrict__ Aq, const u16* __restrict__ Ak,
                                                   const u16* __restrict__ Av, const u16* __restrict__ wq,
                                                   const u16* __restrict__ wk, const u16* __restrict__ wv,
                                                   const float* __restrict__ cosb, const float* __restrict__ sinb,
                                                   u16* __restrict__ Qr, u16* __restrict__ Kr,
                                                   u16* __restrict__ Vt) {
  __shared__ __attribute__((aligned(16))) u16 SH[12288];  // As[64][64] + Bs[128][64]
  u16* As = SH;
  u16* Bs = SH + 4096;
  const int tid = threadIdx.x, lane = tid & 63, w = tid >> 6;
  const int wr = w >> 1, wc = w & 1, lo = lane & 15, hi = lane >> 4;
  const int bx = blockIdx.x, by = blockIdx.y;
  const int m0 = bx * 64;

  const u16 *Ap, *Wp;
  int n0, mode;
  if (by < 8) { Ap = Aq; Wp = wq; n0 = by * 128; mode = 0; }
  else if (by < 10) { Ap = Ak; Wp = wk; n0 = (by - 8) * 128; mode = 1; }
  else { Ap = Av; Wp = wv; n0 = (by - 10) * 128; mode = 2; }
  const u16* Abase = Ap + (size_t)m0 * DM;
  const u16* Wbase = Wp + (size_t)n0 * DM;

  f32x4 acc[2][4];
#pragma unroll
  for (int i = 0; i < 2; i++)
#pragma unroll
    for (int j = 0; j < 4; j++) acc[i][j] = (f32x4){0.f, 0.f, 0.f, 0.f};

  for (int ks = 0; ks < 16; ks++) {
    const int k0 = ks * 64;
    stage_tile<64>(Abase, k0, As, w, lane);
    stage_tile<128>(Wbase, k0, Bs, w, lane);
    __syncthreads();
    short8 af[2][2], bfr[4][2];
#pragma unroll
    for (int mi = 0; mi < 2; mi++)
#pragma unroll
      for (int kk = 0; kk < 2; kk++)
        af[mi][kk] = lds_frag(As, wr * 32 + mi * 16 + lo, kk * 4 + hi);
#pragma unroll
    for (int ni = 0; ni < 4; ni++)
#pragma unroll
      for (int kk = 0; kk < 2; kk++)
        bfr[ni][kk] = lds_frag(Bs, wc * 64 + ni * 16 + lo, kk * 4 + hi);
    __builtin_amdgcn_s_setprio(1);
#pragma unroll
    for (int mi = 0; mi < 2; mi++)
#pragma unroll
      for (int ni = 0; ni < 4; ni++) {
        acc[mi][ni] = __builtin_amdgcn_mfma_f32_16x16x32_bf16(af[mi][0], bfr[ni][0], acc[mi][ni], 0, 0, 0);
        acc[mi][ni] = __builtin_amdgcn_mfma_f32_16x16x32_bf16(af[mi][1], bfr[ni][1], acc[mi][ni], 0, 0, 0);
      }
    __builtin_amdgcn_s_setprio(0);
    __syncthreads();
  }

  if (mode < 2) {
    // ---- RoPE epilogue -> Qr (b,h,s,d) or Kr (b,kh,s,d) ----
    const float scale = (mode == 0) ? 0.18033688f : 1.0f;  // Q: (1/8)*log2(e)
    u16* outp = (mode == 0) ? Qr : Kr;
    const int OH = (mode == 0) ? NHEADS : NKVH;
    const float sgn = (lo & 1) ? 1.0f : -1.0f;
#pragma unroll
    for (int ni = 0; ni < 4; ni++) {
      const int col = n0 + wc * 64 + ni * 16 + lo;
      const int h = col >> 6, d = col & 63, j = d >> 1;
#pragma unroll
      for (int mi = 0; mi < 2; mi++)
#pragma unroll
        for (int r = 0; r < 4; r++) {
          int row = m0 + wr * 32 + mi * 16 + hi * 4 + r;
          int srow = row & (SEQ - 1), bb = row >> 11;
          float v = acc[mi][ni][r];
          float pv = __shfl_xor(v, 1, 64);
          float c = cosb[srow * 32 + j];
          float s = sinb[srow * 32 + j];
          outp[((size_t)(bb * OH + h) * SEQ + srow) * 64 + d] = f2b((v * c + pv * s * sgn) * scale);
        }
    }
  } else {
    // ---- V epilogue: transpose via LDS [128][72] -> Vt (b,kh,d,s) ----
    u16* Tt = SH;  // 128*72 = 9216 u16 (fits in 12288)
#pragma unroll
    for (int mi = 0; mi < 2; mi++)
#pragma unroll
      for (int ni = 0; ni < 4; ni++) {
        const int cl = wc * 64 + ni * 16 + lo;   // feature 0..127
#pragma unroll
        for (int r = 0; r < 4; r++) {
          int rl = wr * 32 + mi * 16 + hi * 4 + r;  // s 0..63
          Tt[cl * 72 + rl] = f2b(acc[mi][ni][r]);
        }
      }
    __syncthreads();
    const int dl = tid >> 1;            // feature 0..127
    const int sh2 = (tid & 1) * 32;     // s-half
    const int dg = n0 + dl;
    const int kh = dg >> 6, drow = dg & 63;
    const int bb = m0 >> 11, sbase = m0 & (SEQ - 1);
    u16* dst = Vt + ((size_t)(bb * NKVH + kh) * 64 + drow) * SEQ + sbase + sh2;
#pragma unroll
    for (int i = 0; i < 4; i++)
      *(uint4*)(dst + i * 8) = *(const uint4*)&Tt[dl * 72 + sh2 + i * 8];
  }
}

// ---------------- Flash attention: LPT, 4 blocks/CU, base+imm fragment addressing ----------------
// LDS layout (bytes): [K0: 0..8191][K1: 8192..16383][V0: 16384..24575][V1: 24576..32767]
// Swizzle key is f-independent for both K-frag rows (kappa+{0,4,32,36}) and V rows (16f+lo),
// so all 16 ds_read addresses = one of 4 lane offsets + compile-time immediate.
__global__ __launch_bounds__(256, 4) void attn_kernel(const u16* __restrict__ Q, const u16* __restrict__ Kb,
                                                      const u16* __restrict__ Vt, u16* __restrict__ AO) {
  __shared__ __attribute__((aligned(16))) u16 SH[16384];
  const int tid = threadIdx.x;
  const int w = tid >> 6, lane = tid & 63;
  const int lo = lane & 15, hi = lane >> 4;
  const int bh = blockIdx.x;
  const int b = bh >> 4, h = bh & 15, kh = h >> 2;
  const int t = 31 - blockIdx.y;         // LPT: longest tiles dispatch first
  const int q0 = t * 64 + w * 16;
  const u16* Qp = Q + (size_t)bh * SEQ * 64;
  const u16* Kp = Kb + (size_t)(b * NKVH + kh) * SEQ * 64;
  const u16* Vp = Vt + (size_t)(b * NKVH + kh) * 64 * SEQ;

  short8 qf[2];
#pragma unroll
  for (int kk = 0; kk < 2; kk++)
    qf[kk] = *(const short8*)(Qp + (size_t)(q0 + lo) * 64 + kk * 32 + hi * 8);

  f32x4 o[4];
#pragma unroll
  for (int nf = 0; nf < 4; nf++) o[nf] = (f32x4){0.f, 0.f, 0.f, 0.f};
  float m = -__builtin_inff(), lsp = 0.f;

  auto key = [](int row) { return (row & 3) | (((row >> 3) & 1) << 2); };

  // hoisted staging lane-pointers (loop-invariant); dest covers 8192B per K/V buffer
  const u16* Ksrc0; const u16* Ksrc1; const u16* Vsrc0; const u16* Vsrc1;
  const int dst0 = w * 1024, dst1 = 4096 + w * 1024;
  {
    int byte0 = dst0 + (lane << 4);
    int row0 = byte0 >> 7;
    int gg0 = ((byte0 >> 4) & 7) ^ key(row0);
    Ksrc0 = Kp + row0 * 64 + gg0 * 8;
    Vsrc0 = Vp + (size_t)row0 * SEQ + gg0 * 8;
    int byte1 = dst1 + (lane << 4);
    int row1 = byte1 >> 7;
    int gg1 = ((byte1 >> 4) & 7) ^ key(row1);
    Ksrc1 = Kp + row1 * 64 + gg1 * 8;
    Vsrc1 = Vp + (size_t)row1 * SEQ + gg1 * 8;
  }
  // bb = buffer byte offset (0 or 8192)
  auto stage2 = [&](int kv0, int bb) {
    gload16(Ksrc0 + kv0 * 64, (char*)SH + bb + dst0);
    gload16(Vsrc0 + kv0, (char*)SH + 16384 + bb + dst0);
    gload16(Ksrc1 + kv0 * 64, (char*)SH + bb + dst1);
    gload16(Vsrc1 + kv0, (char*)SH + 16384 + bb + dst1);
  };

  // ---- 4 lane-computed byte offsets; everything else is an immediate ----
  const int b3 = lo & 3;
  const int gx = hi ^ b3;                      // low 2 bits of swizzled granule (same for K and V)
  const int kOffA = (8 * (lo >> 2) + b3) * 128 + gx * 16 + ((lo >> 2) & 1) * 64;
  const int kOffB = kOffA ^ 64;
  const int vOffA = lo * 128 + gx * 16 + ((lo >> 3) & 1) * 64;
  const int vOffB = vOffA ^ 64;
  const char* SHb = (const char*)SH;
  auto ld16 = [&](int off) { return *(const short8*)(SHb + off); };

  // one chunk: prefetch next, frag reads (base+imm), QK, [mask], softmax+PV, barrier
  auto body = [&](int c, int kb /*0|8192*/, int nbb /*0|8192*/, bool pref, bool maskc) {
    if (pref) stage2((c + 1) * 64, nbb);
    short8 kf0[4], kf1[4];
    kf0[0] = ld16(kOffA + kb);        kf1[0] = ld16(kOffB + kb);
    kf0[1] = ld16(kOffA + kb + 512);  kf1[1] = ld16(kOffB + kb + 512);
    kf0[2] = ld16(kOffA + kb + 4096); kf1[2] = ld16(kOffB + kb + 4096);
    kf0[3] = ld16(kOffA + kb + 4608); kf1[3] = ld16(kOffB + kb + 4608);
    f32x4 sc[4];
#pragma unroll
    for (int f = 0; f < 4; f++) sc[f] = (f32x4){0.f, 0.f, 0.f, 0.f};
    __builtin_amdgcn_s_setprio(1);
#pragma unroll
    for (int f = 0; f < 4; f++) {
      sc[f] = __builtin_amdgcn_mfma_f32_16x16x32_bf16(kf0[f], qf[0], sc[f], 0, 0, 0);
      sc[f] = __builtin_amdgcn_mfma_f32_16x16x32_bf16(kf1[f], qf[1], sc[f], 0, 0, 0);
    }
    __builtin_amdgcn_s_setprio(0);
    short8 vb0[4], vb1[4];
#pragma unroll
    for (int nf = 0; nf < 4; nf++) {
      vb0[nf] = ld16(vOffA + kb + 16384 + nf * 2048);
      vb1[nf] = ld16(vOffB + kb + 16384 + nf * 2048);
    }
    if (maskc) {
      const int kv0 = c * 64;
#pragma unroll
      for (int f = 0; f < 4; f++) {
        int kvb = kv0 + 32 * (f >> 1) + 8 * hi + 4 * (f & 1);
#pragma unroll
        for (int r = 0; r < 4; r++)
          if (kvb + r > q0 + lo) sc[f][r] = -__builtin_inff();
      }
    }
    // ---- softmax + PV ----
    float t0 = fmaxf(fmaxf(sc[0][0], sc[0][1]), fmaxf(sc[0][2], sc[0][3]));
    float t1 = fmaxf(fmaxf(sc[1][0], sc[1][1]), fmaxf(sc[1][2], sc[1][3]));
    float t2 = fmaxf(fmaxf(sc[2][0], sc[2][1]), fmaxf(sc[2][2], sc[2][3]));
    float t3 = fmaxf(fmaxf(sc[3][0], sc[3][1]), fmaxf(sc[3][2], sc[3][3]));
    float lm = fmaxf(fmaxf(t0, t1), fmaxf(t2, t3));
    if (__any(lm - m > 8.f)) {
      float mx = fmaxf(m, lm);
      mx = fmaxf(mx, __shfl_xor(mx, 16, 64));
      mx = fmaxf(mx, __shfl_xor(mx, 32, 64));
      float corr = fexp2(m - mx);
      m = mx;
      lsp *= corr;
      float corrq[4];
#pragma unroll
      for (int r = 0; r < 4; r++) corrq[r] = __shfl(corr, hi * 4 + r, 64);
#pragma unroll
      for (int nf = 0; nf < 4; nf++)
#pragma unroll
        for (int r = 0; r < 4; r++) o[nf][r] *= corrq[r];
    }
    float pv2[4][4];
    float ps[4];
#pragma unroll
    for (int f = 0; f < 4; f++) {
#pragma unroll
      for (int r = 0; r < 4; r++) pv2[f][r] = fexp2(sc[f][r] - m);
      ps[f] = (pv2[f][0] + pv2[f][1]) + (pv2[f][2] + pv2[f][3]);
    }
    lsp += (ps[0] + ps[1]) + (ps[2] + ps[3]);
    union { u32 u[4]; short8 s8; } pa0, pa1;
#pragma unroll
    for (int tt = 0; tt < 4; tt++) {
      int fsel = tt >> 1, r0 = 2 * (tt & 1);
      pa0.u[tt] = cvtpk(pv2[fsel][r0], pv2[fsel][r0 + 1]);
      pa1.u[tt] = cvtpk(pv2[2 + fsel][r0], pv2[2 + fsel][r0 + 1]);
    }
    __builtin_amdgcn_s_setprio(1);
#pragma unroll
    for (int nf = 0; nf < 4; nf++) {
      o[nf] = __builtin_amdgcn_mfma_f32_16x16x32_bf16(pa0.s8, vb0[nf], o[nf], 0, 0, 0);
      o[nf] = __builtin_amdgcn_mfma_f32_16x16x32_bf16(pa1.s8, vb1[nf], o[nf], 0, 0, 0);
    }
    __builtin_amdgcn_s_setprio(0);
    __syncthreads();
  };

  stage2(0, 0);
  __syncthreads();

  int c = 0;
  for (; c + 2 <= t; c += 2) {
    body(c, 0, 8192, true, false);
    body(c + 1, 8192, 0, true, false);
  }
  if (c < t) {  // t == c+1
    body(c, 0, 8192, true, false);
    body(c + 1, 8192, 0, false, true);
  } else {      // t == c
    body(c, 0, 8192, false, true);
  }

  lsp += __shfl_xor(lsp, 16, 64);
  lsp += __shfl_xor(lsp, 32, 64);
  float inv = 1.0f / lsp;
  float invq[4];
#pragma unroll
  for (int r = 0; r < 4; r++) invq[r] = __shfl(inv, hi * 4 + r, 64);
#pragma unroll
  for (int nf = 0; nf < 4; nf++)
#pragma unroll
    for (int r = 0; r < 4; r++) {
      int q = q0 + hi * 4 + r;
      int d = nf * 16 + lo;
      AO[((size_t)(b * SEQ + q) * NHEADS + h) * 64 + d] = f2b(o[nf][r] * invq[r]);
    }
}

// ---------------- output projection: d_out[M,1024] = AO(bf16) @ wo^T(bf16) ----------------
__global__ __launch_bounds__(256, 2) void gemm_out(const u16* __restrict__ A, const u16* __restrict__ W,
                                                   float* __restrict__ Out) {
  __shared__ __attribute__((aligned(16))) u16 SH[12288];
  u16* As = SH;
  u16* Bs = SH + 4096;
  const int tid = threadIdx.x, lane = tid & 63, w = tid >> 6;
  const int wr = w >> 1, wc = w & 1, lo = lane & 15, hi = lane >> 4;
  const int m0 = blockIdx.x * 64, n0 = blockIdx.y * 128;
  const u16* Abase = A + (size_t)m0 * DM;
  const u16* Wbase = W + (size_t)n0 * DM;

  f32x4 acc[2][4];
#pragma unroll
  for (int i = 0; i < 2; i++)
#pragma unroll
    for (int j = 0; j < 4; j++) acc[i][j] = (f32x4){0.f, 0.f, 0.f, 0.f};

  for (int ks = 0; ks < 16; ks++) {
    const int k0 = ks * 64;
    stage_tile<64>(Abase, k0, As, w, lane);
    stage_tile<128>(Wbase, k0, Bs, w, lane);
    __syncthreads();
    short8 af[2][2], bfr[4][2];
#pragma unroll
    for (int mi = 0; mi < 2; mi++)
#pragma unroll
      for (int kk = 0; kk < 2; kk++)
        af[mi][kk] = lds_frag(As, wr * 32 + mi * 16 + lo, kk * 4 + hi);
#pragma unroll
    for (int ni = 0; ni < 4; ni++)
#pragma unroll
      for (int kk = 0; kk < 2; kk++)
        bfr[ni][kk] = lds_frag(Bs, wc * 64 + ni * 16 + lo, kk * 4 + hi);
    __builtin_amdgcn_s_setprio(1);
#pragma unroll
    for (int mi = 0; mi < 2; mi++)
#pragma unroll
      for (int ni = 0; ni < 4; ni++) {
        acc[mi][ni] = __builtin_amdgcn_mfma_f32_16x16x32_bf16(af[mi][0], bfr[ni][0], acc[mi][ni], 0, 0, 0);
        acc[mi][ni] = __builtin_amdgcn_mfma_f32_16x16x32_bf16(af[mi][1], bfr[ni][1], acc[mi][ni], 0, 0, 0);
      }
    __builtin_amdgcn_s_setprio(0);
    __syncthreads();
  }

#pragma unroll
  for (int mi = 0; mi < 2; mi++)
#pragma unroll
    for (int ni = 0; ni < 4; ni++)
#pragma unroll
      for (int r = 0; r < 4; r++) {
        int row = m0 + wr * 32 + mi * 16 + hi * 4 + r;
        int col = n0 + wc * 64 + ni * 16 + lo;
        Out[(size_t)row * DM + col] = acc[mi][ni][r];
      }
}

extern "C" void kernel_launch(void* const* d_in, const int* in_sizes, int n_in,
                              void* d_out, int out_size, void* d_ws, size_t ws_size,
                              hipStream_t stream) {
  const float* query = (const float*)d_in[0];
  const float* key_ = (const float*)d_in[1];
  const float* value = (const float*)d_in[2];
  const float* fcos = (const float*)d_in[3];
  const float* fsin = (const float*)d_in[4];
  const float* wq = (const float*)d_in[5];
  const float* wk = (const float*)d_in[6];
  const float* wv = (const float*)d_in[7];
  const float* wo = (const float*)d_in[8];

  char* ws = (char*)d_ws;
  size_t off = 0;
  auto alloc = [&](size_t elems) {
    u16* p = (u16*)(ws + off);
    off = (off + elems * 2 + 255) & ~(size_t)255;
    return p;
  };
  u16* qf = alloc((size_t)MTOK * DM);
  u16* kf = alloc((size_t)MTOK * DM);
  u16* vf = alloc((size_t)MTOK * DM);
  u16* wqf = alloc((size_t)DM * DM);
  u16* wkf = alloc((size_t)256 * DM);
  u16* wvf = alloc((size_t)256 * DM);
  u16* wof = alloc((size_t)DM * DM);
  u16* Qr = alloc((size_t)MTOK * DM);            // (b,h,s,d) rope'd + scaled
  u16* Kr = alloc((size_t)NB * NKVH * SEQ * 64); // (b,kh,s,d) rope'd
  u16* Vt = alloc((size_t)NB * NKVH * 64 * SEQ); // (b,kh,d,s)
  u16* AO = alloc((size_t)MTOK * DM);            // (b,s,h,d)

  cvt_all<<<3 * 2048 + 1280, 256, 0, stream>>>(query, key_, value, wq, wk, wv, wo,
                                               qf, kf, vf, wqf, wkf, wvf, wof);

  gemm_qkv<<<dim3(64, 12), 256, 0, stream>>>(qf, kf, vf, wqf, wkf, wvf,
                                             fcos, fsin, Qr, Kr, Vt);

  attn_kernel<<<dim3(NB * NHEADS, 32), 256, 0, stream>>>(Qr, Kr, Vt, AO);

  gemm_out<<<dim3(64, 8), 256, 0, stream>>>(AO, wof, (float*)d_out);
}

// Round 16
// 83.194 us; speedup vs baseline: 1.0067x; 1.0067x over previous
//
#include <hip/hip_runtime.h>

#define DM 1024
#define NHEADS 16
#define NKVH 4
#define HDIM 64
#define NB 2
#define SEQ 2048
#define MTOK (NB*SEQ)
#define NEGS (-1e30f)

typedef __attribute__((ext_vector_type(4))) float f32x4;
typedef __attribute__((ext_vector_type(8))) short short8;
typedef unsigned short u16;
typedef unsigned int u32;

__device__ __forceinline__ u16 f2b(float f) {
  u32 i; __builtin_memcpy(&i, &f, 4);
  u32 r = i + 0x7fffu + ((i >> 16) & 1u);
  return (u16)(r >> 16);
}
__device__ __forceinline__ u32 cvtpk(float a, float b) {  // low16=bf16(a), high16=bf16(b)
  u32 r; asm("v_cvt_pk_bf16_f32 %0, %1, %2" : "=v"(r) : "v"(a), "v"(b)); return r;
}
__device__ __forceinline__ float fexp2(float x) {  // raw v_exp_f32 (inputs kept finite)
  float r; asm("v_exp_f32 %0, %1" : "=v"(r) : "v"(x)); return r;
}
__device__ __forceinline__ void gload16(const void* g, void* l) {
  __builtin_amdgcn_global_load_lds((const __attribute__((address_space(1))) u32*)g,
                                   (__attribute__((address_space(3))) u32*)l, 16, 0, 0);
}

// ---------------- fused fp32 -> bf16 convert (all 7 tensors, one launch) ----------------
__device__ __forceinline__ void cvt8(const float* __restrict__ src, u16* __restrict__ dst, int i) {
  float4 a = *(const float4*)(src + i);
  float4 b = *(const float4*)(src + i + 4);
  uint4 pk;
  pk.x = cvtpk(a.x, a.y);
  pk.y = cvtpk(a.z, a.w);
  pk.z = cvtpk(b.x, b.y);
  pk.w = cvtpk(b.z, b.w);
  *(uint4*)(dst + i) = pk;
}

__global__ __launch_bounds__(256) void cvt_all(const float* __restrict__ q, const float* __restrict__ k,
                                               const float* __restrict__ v, const float* __restrict__ wq,
                                               const float* __restrict__ wk, const float* __restrict__ wv,
                                               const float* __restrict__ wo, u16* oq, u16* ok, u16* ov,
                                               u16* owq, u16* owk, u16* owv, u16* owo) {
  const int ACT = (MTOK * DM) / 2048;  // 2048 blocks per activation tensor
  const int BIG = (DM * DM) / 2048;    // 512
  const int SML = (256 * DM) / 2048;   // 128
  int bid = blockIdx.x;
  const float* s; u16* d;
  if (bid < ACT) { s = q; d = oq; }
  else if (bid < 2 * ACT) { s = k; d = ok; bid -= ACT; }
  else if (bid < 3 * ACT) { s = v; d = ov; bid -= 2 * ACT; }
  else {
    bid -= 3 * ACT;
    if (bid < BIG) { s = wq; d = owq; }
    else if (bid < 2 * BIG) { s = wo; d = owo; bid -= BIG; }
    else if (bid < 2 * BIG + SML) { s = wk; d = owk; bid -= 2 * BIG; }
    else { s = wv; d = owv; bid -= 2 * BIG + SML; }
  }
  cvt8(s, d, (bid * 256 + threadIdx.x) * 8);
}

// ---- m97-style bf16 tile staging: NR rows x 64 cols, source-swizzled (T21) ----
template<int NR>
__device__ __forceinline__ void stage_tile(const u16* __restrict__ src, int k0, u16* lds,
                                           int w, int lane) {
#pragma unroll
  for (int i = 0; i < NR / 32; i++) {
    const int base = (i * 4 + w) * 1024;          // byte offset (wave-uniform)
    const int row = (base >> 7) + (lane >> 3);    // 128B per row
    const int g = lane & 7;
    gload16(src + (size_t)row * DM + k0 + ((g ^ (row & 7)) << 3), (char*)lds + base);
  }
}
__device__ __forceinline__ short8 lds_frag(const u16* L, int row, int gr) {
  return *(const short8*)(L + row * 64 + ((gr ^ (row & 7)) << 3));
}

// ---------------- fused QKV projection GEMM (bf16) + RoPE + V-transpose ----------------
__global__ __launch_bounds__(256, 3) void gemm_qkv(const u16* __restrict__ Aq, const u16* __restrict__ Ak,
                                                   const u16* __restrict__ Av, const u16* __restrict__ wq,
                                                   const u16* __restrict__ wk, const u16* __restrict__ wv,
                                                   const float* __restrict__ cosb, const float* __restrict__ sinb,
                                                   u16* __restrict__ Qr, u16* __restrict__ Kr,
                                                   u16* __restrict__ Vt) {
  __shared__ __attribute__((aligned(16))) u16 SH[12288];  // As[64][64] + Bs[128][64]
  u16* As = SH;
  u16* Bs = SH + 4096;
  const int tid = threadIdx.x, lane = tid & 63, w = tid >> 6;
  const int wr = w >> 1, wc = w & 1, lo = lane & 15, hi = lane >> 4;
  const int bx = blockIdx.x, by = blockIdx.y;
  const int m0 = bx * 64;

  const u16 *Ap, *Wp;
  int n0, mode;
  if (by < 8) { Ap = Aq; Wp = wq; n0 = by * 128; mode = 0; }
  else if (by < 10) { Ap = Ak; Wp = wk; n0 = (by - 8) * 128; mode = 1; }
  else { Ap = Av; Wp = wv; n0 = (by - 10) * 128; mode = 2; }
  const u16* Abase = Ap + (size_t)m0 * DM;
  const u16* Wbase = Wp + (size_t)n0 * DM;

  f32x4 acc[2][4];
#pragma unroll
  for (int i = 0; i < 2; i++)
#pragma unroll
    for (int j = 0; j < 4; j++) acc[i][j] = (f32x4){0.f, 0.f, 0.f, 0.f};

  for (int ks = 0; ks < 16; ks++) {
    const int k0 = ks * 64;
    stage_tile<64>(Abase, k0, As, w, lane);
    stage_tile<128>(Wbase, k0, Bs, w, lane);
    __syncthreads();
    short8 af[2][2], bfr[4][2];
#pragma unroll
    for (int mi = 0; mi < 2; mi++)
#pragma unroll
      for (int kk = 0; kk < 2; kk++)
        af[mi][kk] = lds_frag(As, wr * 32 + mi * 16 + lo, kk * 4 + hi);
#pragma unroll
    for (int ni = 0; ni < 4; ni++)
#pragma unroll
      for (int kk = 0; kk < 2; kk++)
        bfr[ni][kk] = lds_frag(Bs, wc * 64 + ni * 16 + lo, kk * 4 + hi);
    __builtin_amdgcn_s_setprio(1);
#pragma unroll
    for (int mi = 0; mi < 2; mi++)
#pragma unroll
      for (int ni = 0; ni < 4; ni++) {
        acc[mi][ni] = __builtin_amdgcn_mfma_f32_16x16x32_bf16(af[mi][0], bfr[ni][0], acc[mi][ni], 0, 0, 0);
        acc[mi][ni] = __builtin_amdgcn_mfma_f32_16x16x32_bf16(af[mi][1], bfr[ni][1], acc[mi][ni], 0, 0, 0);
      }
    __builtin_amdgcn_s_setprio(0);
    __syncthreads();
  }

  if (mode < 2) {
    // ---- RoPE epilogue -> Qr (b,h,s,d) or Kr (b,kh,s,d) ----
    const float scale = (mode == 0) ? 0.18033688f : 1.0f;  // Q: (1/8)*log2(e)
    u16* outp = (mode == 0) ? Qr : Kr;
    const int OH = (mode == 0) ? NHEADS : NKVH;
    const float sgn = (lo & 1) ? 1.0f : -1.0f;
#pragma unroll
    for (int ni = 0; ni < 4; ni++) {
      const int col = n0 + wc * 64 + ni * 16 + lo;
      const int h = col >> 6, d = col & 63, j = d >> 1;
#pragma unroll
      for (int mi = 0; mi < 2; mi++)
#pragma unroll
        for (int r = 0; r < 4; r++) {
          int row = m0 + wr * 32 + mi * 16 + hi * 4 + r;
          int srow = row & (SEQ - 1), bb = row >> 11;
          float v = acc[mi][ni][r];
          float pv = __shfl_xor(v, 1, 64);
          float c = cosb[srow * 32 + j];
          float s = sinb[srow * 32 + j];
          outp[((size_t)(bb * OH + h) * SEQ + srow) * 64 + d] = f2b((v * c + pv * s * sgn) * scale);
        }
    }
  } else {
    // ---- V epilogue: transpose via LDS [128][72] -> Vt (b,kh,d,s) ----
    u16* Tt = SH;  // 128*72 = 9216 u16 (fits in 12288)
#pragma unroll
    for (int mi = 0; mi < 2; mi++)
#pragma unroll
      for (int ni = 0; ni < 4; ni++) {
        const int cl = wc * 64 + ni * 16 + lo;   // feature 0..127
#pragma unroll
        for (int r = 0; r < 4; r++) {
          int rl = wr * 32 + mi * 16 + hi * 4 + r;  // s 0..63
          Tt[cl * 72 + rl] = f2b(acc[mi][ni][r]);
        }
      }
    __syncthreads();
    const int dl = tid >> 1;            // feature 0..127
    const int sh2 = (tid & 1) * 32;     // s-half
    const int dg = n0 + dl;
    const int kh = dg >> 6, drow = dg & 63;
    const int bb = m0 >> 11, sbase = m0 & (SEQ - 1);
    u16* dst = Vt + ((size_t)(bb * NKVH + kh) * 64 + drow) * SEQ + sbase + sh2;
#pragma unroll
    for (int i = 0; i < 4; i++)
      *(uint4*)(dst + i * 8) = *(const uint4*)&Tt[dl * 72 + sh2 + i * 8];
  }
}

// ---------------- Flash attention: R8-verified pairing x R13-verified codegen ----------------
// Block owns q-tiles (tA=p, tB=31-p), 64 rows each. Loop c=0..tB: B computed every chunk,
// A guarded by actA=(c<=tA); K/V fragments shared between subtiles. R13's precomputed
// base+imm LDS addressing; NEGS finite sentinel (no inf/NaN anywhere).
__device__ __forceinline__ void softpv(f32x4 (&sc)[4], float& m, float& lsp, f32x4 (&o)[4],
                                       const short8 (&vb0)[4], const short8 (&vb1)[4], int hi) {
  float t0 = fmaxf(fmaxf(sc[0][0], sc[0][1]), fmaxf(sc[0][2], sc[0][3]));
  float t1 = fmaxf(fmaxf(sc[1][0], sc[1][1]), fmaxf(sc[1][2], sc[1][3]));
  float t2 = fmaxf(fmaxf(sc[2][0], sc[2][1]), fmaxf(sc[2][2], sc[2][3]));
  float t3 = fmaxf(fmaxf(sc[3][0], sc[3][1]), fmaxf(sc[3][2], sc[3][3]));
  float lm = fmaxf(fmaxf(t0, t1), fmaxf(t2, t3));
  if (__any(lm - m > 8.f)) {
    float mx = fmaxf(m, lm);
    mx = fmaxf(mx, __shfl_xor(mx, 16, 64));
    mx = fmaxf(mx, __shfl_xor(mx, 32, 64));
    float corr = fexp2(m - mx);      // finite - finite: never NaN
    m = mx;
    lsp *= corr;
    float corrq[4];
#pragma unroll
    for (int r = 0; r < 4; r++) corrq[r] = __shfl(corr, hi * 4 + r, 64);
#pragma unroll
    for (int nf = 0; nf < 4; nf++)
#pragma unroll
      for (int r = 0; r < 4; r++) o[nf][r] *= corrq[r];
  }
  float pv2[4][4];
  float ps[4];
#pragma unroll
  for (int f = 0; f < 4; f++) {
#pragma unroll
    for (int r = 0; r < 4; r++) pv2[f][r] = fexp2(sc[f][r] - m);  // masked: exp2(-huge)=0
    ps[f] = (pv2[f][0] + pv2[f][1]) + (pv2[f][2] + pv2[f][3]);
  }
  lsp += (ps[0] + ps[1]) + (ps[2] + ps[3]);
  union { u32 u[4]; short8 s8; } pa0, pa1;
#pragma unroll
  for (int tt = 0; tt < 4; tt++) {
    int fsel = tt >> 1, r0 = 2 * (tt & 1);
    pa0.u[tt] = cvtpk(pv2[fsel][r0], pv2[fsel][r0 + 1]);
    pa1.u[tt] = cvtpk(pv2[2 + fsel][r0], pv2[2 + fsel][r0 + 1]);
  }
  __builtin_amdgcn_s_setprio(1);
#pragma unroll
  for (int nf = 0; nf < 4; nf++) {
    o[nf] = __builtin_amdgcn_mfma_f32_16x16x32_bf16(pa0.s8, vb0[nf], o[nf], 0, 0, 0);
    o[nf] = __builtin_amdgcn_mfma_f32_16x16x32_bf16(pa1.s8, vb1[nf], o[nf], 0, 0, 0);
  }
  __builtin_amdgcn_s_setprio(0);
}

__global__ __launch_bounds__(256, 2) void attn_kernel(const u16* __restrict__ Q, const u16* __restrict__ Kb,
                                                      const u16* __restrict__ Vt, u16* __restrict__ AO) {
  __shared__ __attribute__((aligned(16))) u16 SH[16384];
  const int tid = threadIdx.x;
  const int w = tid >> 6, lane = tid & 63;
  const int lo = lane & 15, hi = lane >> 4;
  const int bh = blockIdx.x;
  const int b = bh >> 4, h = bh & 15, kh = h >> 2;
  const int p = blockIdx.y;              // 0..15
  const int tA = p, tB = 31 - p;         // short tile, long tile (R8-verified pairing)
  const int q0A = tA * 64 + w * 16;
  const int q0B = tB * 64 + w * 16;
  const u16* Qp = Q + (size_t)bh * SEQ * 64;
  const u16* Kp = Kb + (size_t)(b * NKVH + kh) * SEQ * 64;
  const u16* Vp = Vt + (size_t)(b * NKVH + kh) * 64 * SEQ;

  short8 qfA[2], qfB[2];
#pragma unroll
  for (int kk = 0; kk < 2; kk++) {
    qfA[kk] = *(const short8*)(Qp + (size_t)(q0A + lo) * 64 + kk * 32 + hi * 8);
    qfB[kk] = *(const short8*)(Qp + (size_t)(q0B + lo) * 64 + kk * 32 + hi * 8);
  }

  f32x4 oA[4], oB[4];
#pragma unroll
  for (int nf = 0; nf < 4; nf++) { oA[nf] = (f32x4){0.f,0.f,0.f,0.f}; oB[nf] = (f32x4){0.f,0.f,0.f,0.f}; }
  float mA = NEGS, lspA = 0.f;
  float mB = NEGS, lspB = 0.f;

  auto key = [](int row) { return (row & 3) | (((row >> 3) & 1) << 2); };

  // hoisted staging lane-pointers (loop-invariant); 8192B per K/V buffer
  const u16* Ksrc0; const u16* Ksrc1; const u16* Vsrc0; const u16* Vsrc1;
  const int dst0 = w * 1024, dst1 = 4096 + w * 1024;
  {
    int byte0 = dst0 + (lane << 4);
    int row0 = byte0 >> 7;
    int gg0 = ((byte0 >> 4) & 7) ^ key(row0);
    Ksrc0 = Kp + row0 * 64 + gg0 * 8;
    Vsrc0 = Vp + (size_t)row0 * SEQ + gg0 * 8;
    int byte1 = dst1 + (lane << 4);
    int row1 = byte1 >> 7;
    int gg1 = ((byte1 >> 4) & 7) ^ key(row1);
    Ksrc1 = Kp + row1 * 64 + gg1 * 8;
    Vsrc1 = Vp + (size_t)row1 * SEQ + gg1 * 8;
  }
  auto stage2 = [&](int kv0, int bb) {  // bb = buffer byte offset (0 or 8192)
    gload16(Ksrc0 + kv0 * 64, (char*)SH + bb + dst0);
    gload16(Vsrc0 + kv0, (char*)SH + 16384 + bb + dst0);
    gload16(Ksrc1 + kv0 * 64, (char*)SH + bb + dst1);
    gload16(Vsrc1 + kv0, (char*)SH + 16384 + bb + dst1);
  };

  // ---- 4 lane-computed byte offsets; everything else is an immediate ----
  const int b3 = lo & 3;
  const int gx = hi ^ b3;
  const int kOffA = (8 * (lo >> 2) + b3) * 128 + gx * 16 + ((lo >> 2) & 1) * 64;
  const int kOffB = kOffA ^ 64;
  const int vOffA = lo * 128 + gx * 16 + ((lo >> 3) & 1) * 64;
  const int vOffB = vOffA ^ 64;
  const char* SHb = (const char*)SH;
  auto ld16 = [&](int off) { return *(const short8*)(SHb + off); };

#define CHUNK(CC, KB, NBB, PREF, LAST)                                                      \
  do {                                                                                      \
    const int c_ = (CC);                                                                    \
    if (PREF) stage2((c_ + 1) * 64, (NBB));                                                 \
    short8 kf0[4], kf1[4];                                                                  \
    kf0[0] = ld16(kOffA + (KB));        kf1[0] = ld16(kOffB + (KB));                        \
    kf0[1] = ld16(kOffA + (KB) + 512);  kf1[1] = ld16(kOffB + (KB) + 512);                  \
    kf0[2] = ld16(kOffA + (KB) + 4096); kf1[2] = ld16(kOffB + (KB) + 4096);                 \
    kf0[3] = ld16(kOffA + (KB) + 4608); kf1[3] = ld16(kOffB + (KB) + 4608);                 \
    const bool actA = (c_ <= tA);                                                           \
    f32x4 scA[4], scB[4];                                                                   \
    _Pragma("unroll")                                                                       \
    for (int f = 0; f < 4; f++) scB[f] = (f32x4){0.f, 0.f, 0.f, 0.f};                       \
    __builtin_amdgcn_s_setprio(1);                                                          \
    _Pragma("unroll")                                                                       \
    for (int f = 0; f < 4; f++) {                                                           \
      scB[f] = __builtin_amdgcn_mfma_f32_16x16x32_bf16(kf0[f], qfB[0], scB[f], 0, 0, 0);    \
      scB[f] = __builtin_amdgcn_mfma_f32_16x16x32_bf16(kf1[f], qfB[1], scB[f], 0, 0, 0);    \
    }                                                                                       \
    __builtin_amdgcn_s_setprio(0);                                                          \
    if (actA) {                                                                             \
      _Pragma("unroll")                                                                     \
      for (int f = 0; f < 4; f++) scA[f] = (f32x4){0.f, 0.f, 0.f, 0.f};                     \
      __builtin_amdgcn_s_setprio(1);                                                        \
      _Pragma("unroll")                                                                     \
      for (int f = 0; f < 4; f++) {                                                         \
        scA[f] = __builtin_amdgcn_mfma_f32_16x16x32_bf16(kf0[f], qfA[0], scA[f], 0, 0, 0);  \
        scA[f] = __builtin_amdgcn_mfma_f32_16x16x32_bf16(kf1[f], qfA[1], scA[f], 0, 0, 0);  \
      }                                                                                     \
      __builtin_amdgcn_s_setprio(0);                                                        \
    }                                                                                       \
    short8 vb0[4], vb1[4];                                                                  \
    _Pragma("unroll")                                                                       \
    for (int nf = 0; nf < 4; nf++) {                                                        \
      vb0[nf] = ld16(vOffA + (KB) + 16384 + nf * 2048);                                     \
      vb1[nf] = ld16(vOffB + (KB) + 16384 + nf * 2048);                                     \
    }                                                                                       \
    const int kv0_ = c_ * 64;                                                               \
    if (LAST) {                                                                             \
      _Pragma("unroll")                                                                     \
      for (int f = 0; f < 4; f++) {                                                         \
        int kvb = kv0_ + 32 * (f >> 1) + 8 * hi + 4 * (f & 1);                              \
        _Pragma("unroll")                                                                   \
        for (int r = 0; r < 4; r++)                                                         \
          if (kvb + r > q0B + lo) scB[f][r] = NEGS;                                         \
      }                                                                                     \
    }                                                                                       \
    softpv(scB, mB, lspB, oB, vb0, vb1, hi);                                                \
    if (actA) {                                                                             \
      if (c_ == tA) {                                                                       \
        _Pragma("unroll")                                                                   \
        for (int f = 0; f < 4; f++) {                                                       \
          int kvb = kv0_ + 32 * (f >> 1) + 8 * hi + 4 * (f & 1);                            \
          _Pragma("unroll")                                                                 \
          for (int r = 0; r < 4; r++)                                                       \
            if (kvb + r > q0A + lo) scA[f][r] = NEGS;                                       \
        }                                                                                   \
      }                                                                                     \
      softpv(scA, mA, lspA, oA, vb0, vb1, hi);                                              \
    }                                                                                       \
    __syncthreads();                                                                        \
  } while (0)

  stage2(0, 0);
  __syncthreads();

  int c = 0;
  for (; c + 2 <= tB; c += 2) {
    CHUNK(c, 0, 8192, true, false);
    CHUNK(c + 1, 8192, 0, true, false);
  }
  if (c < tB) {  // tB == c+1 (tB odd)
    CHUNK(c, 0, 8192, true, false);
    CHUNK(c + 1, 8192, 0, false, true);
  } else {       // tB == c (tB even)
    CHUNK(c, 0, 8192, false, true);
  }
#undef CHUNK

  // finalize both subtiles
#pragma unroll
  for (int t2 = 0; t2 < 2; t2++) {
    float lsp = t2 ? lspB : lspA;
    const int q0 = t2 ? q0B : q0A;
    f32x4* o = t2 ? oB : oA;
    lsp += __shfl_xor(lsp, 16, 64);
    lsp += __shfl_xor(lsp, 32, 64);
    float inv = 1.0f / lsp;
    float invq[4];
#pragma unroll
    for (int r = 0; r < 4; r++) invq[r] = __shfl(inv, hi * 4 + r, 64);
#pragma unroll
    for (int nf = 0; nf < 4; nf++)
#pragma unroll
      for (int r = 0; r < 4; r++) {
        int q = q0 + hi * 4 + r;
        int d = nf * 16 + lo;
        AO[((size_t)(b * SEQ + q) * NHEADS + h) * 64 + d] = f2b(o[nf][r] * invq[r]);
      }
  }
}

// ---------------- output projection: d_out[M,1024] = AO(bf16) @ wo^T(bf16) ----------------
__global__ __launch_bounds__(256, 2) void gemm_out(const u16* __restrict__ A, const u16* __restrict__ W,
                                                   float* __restrict__ Out) {
  __shared__ __attribute__((aligned(16))) u16 SH[12288];
  u16* As = SH;
  u16* Bs = SH + 4096;
  const int tid = threadIdx.x, lane = tid & 63, w = tid >> 6;
  const int wr = w >> 1, wc = w & 1, lo = lane & 15, hi = lane >> 4;
  const int m0 = blockIdx.x * 64, n0 = blockIdx.y * 128;
  const u16* Abase = A + (size_t)m0 * DM;
  const u16* Wbase = W + (size_t)n0 * DM;

  f32x4 acc[2][4];
#pragma unroll
  for (int i = 0; i < 2; i++)
#pragma unroll
    for (int j = 0; j < 4; j++) acc[i][j] = (f32x4){0.f, 0.f, 0.f, 0.f};

  for (int ks = 0; ks < 16; ks++) {
    const int k0 = ks * 64;
    stage_tile<64>(Abase, k0, As, w, lane);
    stage_tile<128>(Wbase, k0, Bs, w, lane);
    __syncthreads();
    short8 af[2][2], bfr[4][2];
#pragma unroll
    for (int mi = 0; mi < 2; mi++)
#pragma unroll
      for (int kk = 0; kk < 2; kk++)
        af[mi][kk] = lds_frag(As, wr * 32 + mi * 16 + lo, kk * 4 + hi);
#pragma unroll
    for (int ni = 0; ni < 4; ni++)
#pragma unroll
      for (int kk = 0; kk < 2; kk++)
        bfr[ni][kk] = lds_frag(Bs, wc * 64 + ni * 16 + lo, kk * 4 + hi);
    __builtin_amdgcn_s_setprio(1);
#pragma unroll
    for (int mi = 0; mi < 2; mi++)
#pragma unroll
      for (int ni = 0; ni < 4; ni++) {
        acc[mi][ni] = __builtin_amdgcn_mfma_f32_16x16x32_bf16(af[mi][0], bfr[ni][0], acc[mi][ni], 0, 0, 0);
        acc[mi][ni] = __builtin_amdgcn_mfma_f32_16x16x32_bf16(af[mi][1], bfr[ni][1], acc[mi][ni], 0, 0, 0);
      }
    __builtin_amdgcn_s_setprio(0);
    __syncthreads();
  }

#pragma unroll
  for (int mi = 0; mi < 2; mi++)
#pragma unroll
    for (int ni = 0; ni < 4; ni++)
#pragma unroll
      for (int r = 0; r < 4; r++) {
        int row = m0 + wr * 32 + mi * 16 + hi * 4 + r;
        int col = n0 + wc * 64 + ni * 16 + lo;
        Out[(size_t)row * DM + col] = acc[mi][ni][r];
      }
}

extern "C" void kernel_launch(void* const* d_in, const int* in_sizes, int n_in,
                              void* d_out, int out_size, void* d_ws, size_t ws_size,
                              hipStream_t stream) {
  const float* query = (const float*)d_in[0];
  const float* key_ = (const float*)d_in[1];
  const float* value = (const float*)d_in[2];
  const float* fcos = (const float*)d_in[3];
  const float* fsin = (const float*)d_in[4];
  const float* wq = (const float*)d_in[5];
  const float* wk = (const float*)d_in[6];
  const float* wv = (const float*)d_in[7];
  const float* wo = (const float*)d_in[8];

  char* ws = (char*)d_ws;
  size_t off = 0;
  auto alloc = [&](size_t elems) {
    u16* p = (u16*)(ws + off);
    off = (off + elems * 2 + 255) & ~(size_t)255;
    return p;
  };
  u16* qf = alloc((size_t)MTOK * DM);
  u16* kf = alloc((size_t)MTOK * DM);
  u16* vf = alloc((size_t)MTOK * DM);
  u16* wqf = alloc((size_t)DM * DM);
  u16* wkf = alloc((size_t)256 * DM);
  u16* wvf = alloc((size_t)256 * DM);
  u16* wof = alloc((size_t)DM * DM);
  u16* Qr = alloc((size_t)MTOK * DM);            // (b,h,s,d) rope'd + scaled
  u16* Kr = alloc((size_t)NB * NKVH * SEQ * 64); // (b,kh,s,d) rope'd
  u16* Vt = alloc((size_t)NB * NKVH * 64 * SEQ); // (b,kh,d,s)
  u16* AO = alloc((size_t)MTOK * DM);            // (b,s,h,d)

  cvt_all<<<3 * 2048 + 1280, 256, 0, stream>>>(query, key_, value, wq, wk, wv, wo,
                                               qf, kf, vf, wqf, wkf, wvf, wof);

  gemm_qkv<<<dim3(64, 12), 256, 0, stream>>>(qf, kf, vf, wqf, wkf, wvf,
                                             fcos, fsin, Qr, Kr, Vt);

  attn_kernel<<<dim3(NB * NHEADS, 16), 256, 0, stream>>>(Qr, Kr, Vt, AO);

  gemm_out<<<dim3(64, 8), 256, 0, stream>>>(AO, wof, (float*)d_out);
}